// Round 20
// baseline (244.368 us; speedup 1.0000x reference)
//
#include <hip/hip_runtime.h>

#define DH 30
#define SLOPE 0.01f

typedef float v2 __attribute__((ext_vector_type(2)));
#define SB() __builtin_amdgcn_sched_barrier(0)

// LDS layout (floats): W1[9][32]@0, W2[30][32]@288, W3[30][32]@1248,
// b1[32]@2208, b2[32]@2240, b3[32]@2272, W4[32]@2304, b4@2336. Pads zero.
#define W1_OFF 0
#define W2_OFF 288
#define W3_OFF 1248
#define B1_OFF 2208
#define B2_OFF 2240
#define B3_OFF 2272
#define W4_OFF 2304
#define B4_OFF 2336

// ws layout: W3p[30][32]@0, W2p[30][32]@960 (128B-aligned rows, zero pads).
#define WS_W3 0
#define WS_W2 960

__global__ __launch_bounds__(256) void pack_w(
    const float* __restrict__ W2, const float* __restrict__ W3,
    float* __restrict__ ws)
{
    for (int idx = threadIdx.x; idx < 1920; idx += 256) {
        float v = 0.f;
        if (idx < 960)  { int r = idx >> 5, c = idx & 31; v = (c < DH) ? W3[r * DH + c] : 0.f; }
        else            { int t = idx - 960; int r = t >> 5, c = t & 31; v = (c < DH) ? W2[r * DH + c] : 0.f; }
        ws[idx] = v;
    }
}

// Launder a uniform pointer through __shfl: divergence analysis marks it
// divergent -> loads stay on the VECTOR memory path (global_load, counted
// vmcnt). Uniform-address VMEM loads coalesce to ONE L1 transaction +
// broadcast (unlike the LDS port, which replicates bytes per lane:
// R13=R17). R9 proved laundering works but exploded WITHOUT fences;
// R16/R17 proved per-row SB() fences tame vector-result hoisting.
__device__ __forceinline__ const float* vptr(const float* p) {
    unsigned long long a = (unsigned long long)p;
    int lo = __shfl((int)(unsigned)(a & 0xffffffffull), 0);
    int hi = __shfl((int)(unsigned)(a >> 32), 0);
    return (const float*)((((unsigned long long)(unsigned)hi) << 32) |
                          (unsigned long long)(unsigned)lo);
}

// Three-pipe split (R18/R19: two-pipe max-pole floor ~120us measured ~160).
// LDS 48 rows: fwd W1,W2 + bwd W1. SMEM 45 rows: bwd W3 + bwd W2 k<15.
// VMEM 45 rows: fwd W3 + bwd W2 k>=15 (laundered ws, fenced per row).
__global__ __launch_bounds__(256, 3) void mlp_fwdbwd(
    const float4* __restrict__ pe,
    const float*  __restrict__ q,
    const float4* __restrict__ s,
    const float* __restrict__ W1, const float* __restrict__ b1,
    const float* __restrict__ W2, const float* __restrict__ b2,
    const float* __restrict__ W3, const float* __restrict__ b3,
    const float* __restrict__ W4, const float* __restrict__ b4,
    const float* __restrict__ wsp,
    float* __restrict__ dout, int n)
{
    __shared__ float lw[2368];
    const int tid = threadIdx.x;
    for (int idx = tid; idx < 2368; idx += 256) {
        float v = 0.f;
        if (idx < 288)        { int tt = idx,        r = tt >> 5, c = tt & 31; v = (c < DH) ? W1[r * DH + c] : 0.f; }
        else if (idx < 1248)  { int tt = idx - 288,  r = tt >> 5, c = tt & 31; v = (c < DH) ? W2[r * DH + c] : 0.f; }
        else if (idx < 2208)  { int tt = idx - 1248, r = tt >> 5, c = tt & 31; v = (c < DH) ? W3[r * DH + c] : 0.f; }
        else if (idx < 2240)  { int c = idx - 2208; v = (c < DH) ? b1[c] : 0.f; }
        else if (idx < 2272)  { int c = idx - 2240; v = (c < DH) ? b2[c] : 0.f; }
        else if (idx < 2304)  { int c = idx - 2272; v = (c < DH) ? b3[c] : 0.f; }
        else if (idx < 2336)  { int c = idx - 2304; v = (c < DH) ? W4[c] : 0.f; }
        else if (idx == 2336) { v = b4[0]; }
        lw[idx] = v;
    }
    __syncthreads();

    const int i = blockIdx.x * 256 + tid;
    if (i >= n) return;

    const float* wv = vptr(wsp);   // divergent alias -> VMEM pipe

    const float4 vpe = pe[i];
    const float4 vs  = s[i];
    const float  vq  = q[i];
    float x[9] = { vpe.x, vpe.y, vpe.z, vpe.w, vq, vs.x, vs.y, vs.z, vs.w };

    v2 acc[15];
    v2 hh[15];
    unsigned m1 = 0, m2 = 0, m3 = 0;
    const v2 slope2 = { SLOPE, SLOPE };

    // LDS row fma (7x float4 + 1x v2), jj ascending -> bit-identical chain.
    #define ROW_FMA_LDS(OFF, k, sv)                                           \
    {                                                                         \
        const float4* Wr4 = reinterpret_cast<const float4*>(lw + OFF + (k)*32);\
        const v2*     Wr2 = reinterpret_cast<const v2*>(lw + OFF + (k)*32);   \
        _Pragma("unroll")                                                     \
        for (int j4 = 0; j4 < 7; ++j4) {                                      \
            const float4 w = Wr4[j4];                                         \
            const v2 wlo = { w.x, w.y };                                      \
            const v2 whi = { w.z, w.w };                                      \
            acc[2*j4]   = __builtin_elementwise_fma(sv, wlo, acc[2*j4]);      \
            acc[2*j4+1] = __builtin_elementwise_fma(sv, whi, acc[2*j4+1]);    \
        }                                                                     \
        acc[14] = __builtin_elementwise_fma(sv, Wr2[14], acc[14]);            \
    }
    // VMEM row fma from packed ws (same order -> bit-identical chain).
    #define ROW_FMA_VM(OFF, k, sv)                                            \
    {                                                                         \
        const float4* Wr4 = reinterpret_cast<const float4*>(wv + OFF + (k)*32);\
        const v2*     Wr2 = reinterpret_cast<const v2*>(wv + OFF + (k)*32);   \
        _Pragma("unroll")                                                     \
        for (int j4 = 0; j4 < 7; ++j4) {                                      \
            const float4 w = Wr4[j4];                                         \
            const v2 wlo = { w.x, w.y };                                      \
            const v2 whi = { w.z, w.w };                                      \
            acc[2*j4]   = __builtin_elementwise_fma(sv, wlo, acc[2*j4]);      \
            acc[2*j4+1] = __builtin_elementwise_fma(sv, whi, acc[2*j4+1]);    \
        }                                                                     \
        acc[14] = __builtin_elementwise_fma(sv, Wr2[14], acc[14]);            \
    }

    // ---- layer 1 (LDS) ----
    #pragma unroll
    for (int jj = 0; jj < 15; ++jj) acc[jj] = (v2){0.f, 0.f};
    #pragma unroll
    for (int k = 0; k < 9; ++k) {
        const v2 xv = { x[k], x[k] };
        ROW_FMA_LDS(W1_OFF, k, xv);
        SB();
    }
    {
        const v2* bv = reinterpret_cast<const v2*>(lw + B1_OFF);
        #pragma unroll
        for (int jj = 0; jj < 15; ++jj) {
            const v2 z = acc[jj] + bv[jj];
            if (z.x > 0.f) m1 |= (1u << (2*jj));
            if (z.y > 0.f) m1 |= (1u << (2*jj+1));
            hh[jj] = __builtin_elementwise_max(z, z * slope2);  // bit-identical LeakyReLU
        }
    }
    SB();

    // ---- layer 2 (LDS) ----
    #pragma unroll
    for (int jj = 0; jj < 15; ++jj) acc[jj] = (v2){0.f, 0.f};
    #pragma unroll
    for (int k = 0; k < DH; ++k) {
        const float hk = hh[k >> 1][k & 1];
        const v2 hv = { hk, hk };
        ROW_FMA_LDS(W2_OFF, k, hv);
        SB();
    }
    {
        const v2* bv = reinterpret_cast<const v2*>(lw + B2_OFF);
        #pragma unroll
        for (int jj = 0; jj < 15; ++jj) {
            const v2 z = acc[jj] + bv[jj];
            if (z.x > 0.f) m2 |= (1u << (2*jj));
            if (z.y > 0.f) m2 |= (1u << (2*jj+1));
            hh[jj] = __builtin_elementwise_max(z, z * slope2);
        }
    }
    SB();

    // ---- layer 3 (VMEM from packed ws) ----
    #pragma unroll
    for (int jj = 0; jj < 15; ++jj) acc[jj] = (v2){0.f, 0.f};
    #pragma unroll
    for (int k = 0; k < DH; ++k) {
        const float hk = hh[k >> 1][k & 1];
        const v2 hv = { hk, hk };
        ROW_FMA_VM(WS_W3, k, hv);
        SB();
    }
    // output dot: scalar, j ascending (bit-identical to R13..R19)
    const float* b3p = lw + B3_OFF;
    const float* W4p = lw + W4_OFF;
    float outv = 0.f;
    #pragma unroll
    for (int j = 0; j < DH; ++j) {
        const float z = acc[j >> 1][j & 1] + b3p[j];
        if (z > 0.f) m3 |= (1u << j);
        const float hz = (z > 0.f) ? z : SLOPE * z;
        outv = fmaf(hz, W4p[j], outv);
    }
    outv += lw[B4_OFF];
    SB();

    // ---- backward (mask-driven; value-continuous) ----
    v2 g3[16];
    {
        const v2* w4v = reinterpret_cast<const v2*>(W4p);
        #pragma unroll
        for (int jj = 0; jj < 15; ++jj) {
            const v2 w = w4v[jj];
            g3[jj].x = ((m3 >> (2*jj))   & 1u) ? w.x : SLOPE * w.x;
            g3[jj].y = ((m3 >> (2*jj+1)) & 1u) ? w.y : SLOPE * w.y;
        }
        g3[15] = (v2){0.f, 0.f};
    }
    // g2: W3 rows via SMEM (uniform wsp, packed; SGPR self-caps hoisting)
    v2 g2[16];
    #pragma unroll
    for (int k = 0; k < DH; ++k) {
        v2 d = (v2){0.f, 0.f};
        const v2* Wr = reinterpret_cast<const v2*>(wsp + WS_W3 + k * 32);
        #pragma unroll
        for (int jj = 0; jj < 16; ++jj)
            d = __builtin_elementwise_fma(g3[jj], Wr[jj], d);
        const float dot = d.x + d.y;
        g2[k >> 1][k & 1] = ((m2 >> k) & 1u) ? dot : SLOPE * dot;
    }
    g2[15] = (v2){0.f, 0.f};
    // g1: W2 rows k<15 via SMEM, k>=15 via VMEM (laundered, fenced)
    v2 g1[15];
    #pragma unroll
    for (int k = 0; k < 15; ++k) {
        v2 d = (v2){0.f, 0.f};
        const v2* Wr = reinterpret_cast<const v2*>(wsp + WS_W2 + k * 32);
        #pragma unroll
        for (int jj = 0; jj < 16; ++jj)
            d = __builtin_elementwise_fma(g2[jj], Wr[jj], d);
        const float dot = d.x + d.y;
        g1[k >> 1][k & 1] = ((m1 >> k) & 1u) ? dot : SLOPE * dot;
    }
    #pragma unroll
    for (int k = 15; k < DH; ++k) {
        const float4* Wr4 = reinterpret_cast<const float4*>(wv + WS_W2 + k * 32);
        const v2*     Wr2 = reinterpret_cast<const v2*>(wv + WS_W2 + k * 32);
        v2 da = (v2){0.f, 0.f}, db = (v2){0.f, 0.f};
        #pragma unroll
        for (int j4 = 0; j4 < 7; ++j4) {
            const float4 w = Wr4[j4];
            const v2 wlo = { w.x, w.y };
            const v2 whi = { w.z, w.w };
            da = __builtin_elementwise_fma(g2[2*j4],   wlo, da);
            db = __builtin_elementwise_fma(g2[2*j4+1], whi, db);
        }
        da = __builtin_elementwise_fma(g2[14], Wr2[14], da);
        const float dot = (da.x + da.y) + (db.x + db.y);
        g1[k >> 1][k & 1] = ((m1 >> k) & 1u) ? dot : SLOPE * dot;
        SB();
    }
    // gx: W1 rows via LDS
    float gx[9];
    #pragma unroll
    for (int k = 0; k < 9; ++k) {
        const float4* Wr4 = reinterpret_cast<const float4*>(lw + W1_OFF + k * 32);
        const v2*     Wr2 = reinterpret_cast<const v2*>(lw + W1_OFF + k * 32);
        v2 da = (v2){0.f, 0.f}, db = (v2){0.f, 0.f};
        #pragma unroll
        for (int j4 = 0; j4 < 7; ++j4) {
            const float4 w = Wr4[j4];
            const v2 wlo = { w.x, w.y };
            const v2 whi = { w.z, w.w };
            da = __builtin_elementwise_fma(g1[2*j4],   wlo, da);
            db = __builtin_elementwise_fma(g1[2*j4+1], whi, db);
        }
        da = __builtin_elementwise_fma(g1[14], Wr2[14], da);
        gx[k] = (da.x + da.y) + (db.x + db.y);
        SB();
    }

    // ---- stores: [out(N) | h_s(4N) | h_q(N) | h_pe(4N)] ----
    dout[i] = outv;
    float4* hs = reinterpret_cast<float4*>(dout + (size_t)n);
    hs[i] = make_float4(gx[5], gx[6], gx[7], gx[8]);
    dout[(size_t)5 * n + i] = gx[4];
    float4* hpe = reinterpret_cast<float4*>(dout + (size_t)6 * n);
    hpe[i] = make_float4(gx[0], gx[1], gx[2], gx[3]);
}

extern "C" void kernel_launch(void* const* d_in, const int* in_sizes, int n_in,
                              void* d_out, int out_size, void* d_ws, size_t ws_size,
                              hipStream_t stream) {
    const int n = in_sizes[1];  // input_q has N elements
    float* ws = (float*)d_ws;
    hipLaunchKernelGGL(pack_w, dim3(1), dim3(256), 0, stream,
        (const float*)d_in[5], (const float*)d_in[7], ws);
    const int blocks = (n + 255) / 256;
    hipLaunchKernelGGL(mlp_fwdbwd, dim3(blocks), dim3(256), 0, stream,
        (const float4*)d_in[0], (const float*)d_in[1], (const float4*)d_in[2],
        (const float*)d_in[3], (const float*)d_in[4],
        (const float*)d_in[5], (const float*)d_in[6],
        (const float*)d_in[7], (const float*)d_in[8],
        (const float*)d_in[9], (const float*)d_in[10],
        (const float*)ws, (float*)d_out, n);
}

// Round 21
// 134.057 us; speedup vs baseline: 1.8229x; 1.8229x over previous
//
#include <hip/hip_runtime.h>

#define DH 30
#define SLOPE 0.01f

typedef float v2 __attribute__((ext_vector_type(2)));
#define SB() __builtin_amdgcn_sched_barrier(0)

// LDS layout (floats): W1[9][32]@0, W2[30][32]@288, W3[30][32]@1248,
// b1[32]@2208, b2[32]@2240, b3[32]@2272, W4[32]@2304, b4@2336. Pads zero.
#define W1_OFF 0
#define W2_OFF 288
#define W3_OFF 1248
#define B1_OFF 2208
#define B2_OFF 2240
#define B3_OFF 2272
#define W4_OFF 2304
#define B4_OFF 2336

// R18 champion (fwd-LDS || bwd-SMEM pipe split, 134us) + paired backward
// k-iterations: two independent row-dots per step so both rows' s_loads
// issue before the shared lgkmcnt drain -> SMEM wait-points ~halve (SMEM
// is wait-point-bound: R11/R17). Pipe inventory closed: LDS replicates
// bytes (R13=R17), SMEM waits are uncounted-drain (R12), VMEM is either
// hoist-explosive (R9) or fence-serial (R20). Forward = R18 verbatim.
__global__ __launch_bounds__(256, 3) void mlp_fwdbwd(
    const float4* __restrict__ pe,
    const float*  __restrict__ q,
    const float4* __restrict__ s,
    const float* __restrict__ W1, const float* __restrict__ b1,
    const float* __restrict__ W2, const float* __restrict__ b2,
    const float* __restrict__ W3, const float* __restrict__ b3,
    const float* __restrict__ W4, const float* __restrict__ b4,
    float* __restrict__ dout, int n)
{
    __shared__ float lw[2368];
    const int tid = threadIdx.x;
    for (int idx = tid; idx < 2368; idx += 256) {
        float v = 0.f;
        if (idx < 288)        { int tt = idx,        r = tt >> 5, c = tt & 31; v = (c < DH) ? W1[r * DH + c] : 0.f; }
        else if (idx < 1248)  { int tt = idx - 288,  r = tt >> 5, c = tt & 31; v = (c < DH) ? W2[r * DH + c] : 0.f; }
        else if (idx < 2208)  { int tt = idx - 1248, r = tt >> 5, c = tt & 31; v = (c < DH) ? W3[r * DH + c] : 0.f; }
        else if (idx < 2240)  { int c = idx - 2208; v = (c < DH) ? b1[c] : 0.f; }
        else if (idx < 2272)  { int c = idx - 2240; v = (c < DH) ? b2[c] : 0.f; }
        else if (idx < 2304)  { int c = idx - 2272; v = (c < DH) ? b3[c] : 0.f; }
        else if (idx < 2336)  { int c = idx - 2304; v = (c < DH) ? W4[c] : 0.f; }
        else if (idx == 2336) { v = b4[0]; }
        lw[idx] = v;
    }
    __syncthreads();

    const int i = blockIdx.x * 256 + tid;
    if (i >= n) return;

    const float4 vpe = pe[i];
    const float4 vs  = s[i];
    const float  vq  = q[i];
    float x[9] = { vpe.x, vpe.y, vpe.z, vpe.w, vq, vs.x, vs.y, vs.z, vs.w };

    v2 acc[15];
    v2 hh[15];
    unsigned m1 = 0, m2 = 0, m3 = 0;
    const v2 slope2 = { SLOPE, SLOPE };

    // row-wide fma: 7x float4 + 1x v2 LDS reads; per-jj fma order identical
    // to R13/R17/R18 -> forward bit-identical. SB() per row (R16 lesson).
    #define ROW_FMA(OFF, k, sv)                                               \
    {                                                                         \
        const float4* Wr4 = reinterpret_cast<const float4*>(lw + OFF + (k)*32);\
        const v2*     Wr2 = reinterpret_cast<const v2*>(lw + OFF + (k)*32);   \
        _Pragma("unroll")                                                     \
        for (int j4 = 0; j4 < 7; ++j4) {                                      \
            const float4 w = Wr4[j4];                                         \
            const v2 wlo = { w.x, w.y };                                      \
            const v2 whi = { w.z, w.w };                                      \
            acc[2*j4]   = __builtin_elementwise_fma(sv, wlo, acc[2*j4]);      \
            acc[2*j4+1] = __builtin_elementwise_fma(sv, whi, acc[2*j4+1]);    \
        }                                                                     \
        acc[14] = __builtin_elementwise_fma(sv, Wr2[14], acc[14]);            \
    }

    // ---- layer 1 ----
    #pragma unroll
    for (int jj = 0; jj < 15; ++jj) acc[jj] = (v2){0.f, 0.f};
    #pragma unroll
    for (int k = 0; k < 9; ++k) {
        const v2 xv = { x[k], x[k] };
        ROW_FMA(W1_OFF, k, xv);
        SB();
    }
    {
        const v2* bv = reinterpret_cast<const v2*>(lw + B1_OFF);
        #pragma unroll
        for (int jj = 0; jj < 15; ++jj) {
            const v2 z = acc[jj] + bv[jj];
            if (z.x > 0.f) m1 |= (1u << (2*jj));
            if (z.y > 0.f) m1 |= (1u << (2*jj+1));
            hh[jj] = __builtin_elementwise_max(z, z * slope2);  // bit-identical LeakyReLU
        }
    }
    SB();

    // ---- layer 2 ----
    #pragma unroll
    for (int jj = 0; jj < 15; ++jj) acc[jj] = (v2){0.f, 0.f};
    #pragma unroll
    for (int k = 0; k < DH; ++k) {
        const float hk = hh[k >> 1][k & 1];
        const v2 hv = { hk, hk };
        ROW_FMA(W2_OFF, k, hv);
        SB();
    }
    {
        const v2* bv = reinterpret_cast<const v2*>(lw + B2_OFF);
        #pragma unroll
        for (int jj = 0; jj < 15; ++jj) {
            const v2 z = acc[jj] + bv[jj];
            if (z.x > 0.f) m2 |= (1u << (2*jj));
            if (z.y > 0.f) m2 |= (1u << (2*jj+1));
            hh[jj] = __builtin_elementwise_max(z, z * slope2);
        }
    }
    SB();

    // ---- layer 3 ----
    #pragma unroll
    for (int jj = 0; jj < 15; ++jj) acc[jj] = (v2){0.f, 0.f};
    #pragma unroll
    for (int k = 0; k < DH; ++k) {
        const float hk = hh[k >> 1][k & 1];
        const v2 hv = { hk, hk };
        ROW_FMA(W3_OFF, k, hv);
        SB();
    }
    // output dot: scalar, j ascending (bit-identical to R13..R18)
    const float* b3p = lw + B3_OFF;
    const float* W4p = lw + W4_OFF;
    float outv = 0.f;
    #pragma unroll
    for (int j = 0; j < DH; ++j) {
        const float z = acc[j >> 1][j & 1] + b3p[j];
        if (z > 0.f) m3 |= (1u << j);
        const float hz = (z > 0.f) ? z : SLOPE * z;
        outv = fmaf(hz, W4p[j], outv);
    }
    outv += lw[B4_OFF];
    SB();

    // ---- backward: SMEM pipe (s_load -> SGPR operand), k-PAIRED so two
    // rows' s_loads share one lgkmcnt drain. Value-continuous, mask-driven.
    v2 g3[15];
    {
        const v2* w4v = reinterpret_cast<const v2*>(W4p);
        #pragma unroll
        for (int jj = 0; jj < 15; ++jj) {
            const v2 w = w4v[jj];
            g3[jj].x = ((m3 >> (2*jj))   & 1u) ? w.x : SLOPE * w.x;
            g3[jj].y = ((m3 >> (2*jj+1)) & 1u) ? w.y : SLOPE * w.y;
        }
    }
    v2 g2[15];
    #pragma unroll
    for (int k = 0; k < DH; k += 2) {
        v2 dA = (v2){0.f, 0.f}, dB = (v2){0.f, 0.f};
        const v2* WrA = reinterpret_cast<const v2*>(W3 + k * DH);
        const v2* WrB = reinterpret_cast<const v2*>(W3 + (k + 1) * DH);
        #pragma unroll
        for (int jj = 0; jj < 15; ++jj) {
            dA = __builtin_elementwise_fma(g3[jj], WrA[jj], dA);
            dB = __builtin_elementwise_fma(g3[jj], WrB[jj], dB);
        }
        const float dotA = dA.x + dA.y;
        const float dotB = dB.x + dB.y;
        g2[k >> 1].x = ((m2 >> k)       & 1u) ? dotA : SLOPE * dotA;
        g2[k >> 1].y = ((m2 >> (k + 1)) & 1u) ? dotB : SLOPE * dotB;
    }
    v2 g1[15];
    #pragma unroll
    for (int k = 0; k < DH; k += 2) {
        v2 dA = (v2){0.f, 0.f}, dB = (v2){0.f, 0.f};
        const v2* WrA = reinterpret_cast<const v2*>(W2 + k * DH);
        const v2* WrB = reinterpret_cast<const v2*>(W2 + (k + 1) * DH);
        #pragma unroll
        for (int jj = 0; jj < 15; ++jj) {
            dA = __builtin_elementwise_fma(g2[jj], WrA[jj], dA);
            dB = __builtin_elementwise_fma(g2[jj], WrB[jj], dB);
        }
        const float dotA = dA.x + dA.y;
        const float dotB = dB.x + dB.y;
        g1[k >> 1].x = ((m1 >> k)       & 1u) ? dotA : SLOPE * dotA;
        g1[k >> 1].y = ((m1 >> (k + 1)) & 1u) ? dotB : SLOPE * dotB;
    }
    float gx[9];
    #pragma unroll
    for (int k = 0; k < 9; ++k) {
        v2 d = (v2){0.f, 0.f};
        const v2* Wr = reinterpret_cast<const v2*>(W1 + k * DH);
        #pragma unroll
        for (int jj = 0; jj < 15; ++jj)
            d = __builtin_elementwise_fma(g1[jj], Wr[jj], d);
        gx[k] = d.x + d.y;
    }

    // ---- stores: [out(N) | h_s(4N) | h_q(N) | h_pe(4N)] ----
    dout[i] = outv;
    float4* hs = reinterpret_cast<float4*>(dout + (size_t)n);
    hs[i] = make_float4(gx[5], gx[6], gx[7], gx[8]);
    dout[(size_t)5 * n + i] = gx[4];
    float4* hpe = reinterpret_cast<float4*>(dout + (size_t)6 * n);
    hpe[i] = make_float4(gx[0], gx[1], gx[2], gx[3]);
}

extern "C" void kernel_launch(void* const* d_in, const int* in_sizes, int n_in,
                              void* d_out, int out_size, void* d_ws, size_t ws_size,
                              hipStream_t stream) {
    const int n = in_sizes[1];  // input_q has N elements
    const int blocks = (n + 255) / 256;
    hipLaunchKernelGGL(mlp_fwdbwd, dim3(blocks), dim3(256), 0, stream,
        (const float4*)d_in[0], (const float*)d_in[1], (const float4*)d_in[2],
        (const float*)d_in[3], (const float*)d_in[4],
        (const float*)d_in[5], (const float*)d_in[6],
        (const float*)d_in[7], (const float*)d_in[8],
        (const float*)d_in[9], (const float*)d_in[10],
        (float*)d_out, n);
}

// Round 22
// 127.617 us; speedup vs baseline: 1.9149x; 1.0505x over previous
//
#include <hip/hip_runtime.h>

#define DH 30
#define SLOPE 0.01f

typedef float v2 __attribute__((ext_vector_type(2)));
#define SB() __builtin_amdgcn_sched_barrier(0)

// LDS layout (floats): W1[9][32]@0, W2[30][32]@288, W3[30][32]@1248,
// b1[32]@2208, b2[32]@2240, b3[32]@2272, W4[32]@2304, b4@2336. Pads zero.
#define W1_OFF 0
#define W2_OFF 288
#define W3_OFF 1248
#define B1_OFF 2208
#define B2_OFF 2240
#define B3_OFF 2272
#define W4_OFF 2304
#define B4_OFF 2336

// R22: block-parity pipe mixing. R18/R21 sit at the two-pipe floor
// (~160/dispatch = max-pole 120 + ~25% overlap loss). The loss is phase
// correlation: all waves do fwd(LDS-heavy) then bwd(SMEM-heavy) together,
// so each pipe saturates while the other idles. Fix: even blocks run
// fwd-LDS/bwd-SMEM, odd blocks run fwd-SMEM/bwd-LDS -> at any instant
// both pipes serve ~half the waves. Same exact values + op order on all
// paths -> bit-identical output. Fences on all LDS rows (R16), none on
// SMEM (SGPR budget self-caps, R8).
__global__ __launch_bounds__(256, 3) void mlp_fwdbwd(
    const float4* __restrict__ pe,
    const float*  __restrict__ q,
    const float4* __restrict__ s,
    const float* __restrict__ W1, const float* __restrict__ b1,
    const float* __restrict__ W2, const float* __restrict__ b2,
    const float* __restrict__ W3, const float* __restrict__ b3,
    const float* __restrict__ W4, const float* __restrict__ b4,
    float* __restrict__ dout, int n)
{
    __shared__ float lw[2368];
    const int tid = threadIdx.x;
    for (int idx = tid; idx < 2368; idx += 256) {
        float v = 0.f;
        if (idx < 288)        { int tt = idx,        r = tt >> 5, c = tt & 31; v = (c < DH) ? W1[r * DH + c] : 0.f; }
        else if (idx < 1248)  { int tt = idx - 288,  r = tt >> 5, c = tt & 31; v = (c < DH) ? W2[r * DH + c] : 0.f; }
        else if (idx < 2208)  { int tt = idx - 1248, r = tt >> 5, c = tt & 31; v = (c < DH) ? W3[r * DH + c] : 0.f; }
        else if (idx < 2240)  { int c = idx - 2208; v = (c < DH) ? b1[c] : 0.f; }
        else if (idx < 2272)  { int c = idx - 2240; v = (c < DH) ? b2[c] : 0.f; }
        else if (idx < 2304)  { int c = idx - 2272; v = (c < DH) ? b3[c] : 0.f; }
        else if (idx < 2336)  { int c = idx - 2304; v = (c < DH) ? W4[c] : 0.f; }
        else if (idx == 2336) { v = b4[0]; }
        lw[idx] = v;
    }
    __syncthreads();

    const int i = blockIdx.x * 256 + tid;
    if (i >= n) return;

    const float4 vpe = pe[i];
    const float4 vs  = s[i];
    const float  vq  = q[i];
    float x[9] = { vpe.x, vpe.y, vpe.z, vpe.w, vq, vs.x, vs.y, vs.z, vs.w };

    v2 acc[15];
    v2 hh[15];
    unsigned m1 = 0, m2 = 0, m3 = 0;
    const v2 slope2 = { SLOPE, SLOPE };
    float outv;
    float gx[9];

    // LDS row fma (7x float4 + 1x v2), jj ascending.
    #define ROW_FMA(OFF, k, sv)                                               \
    {                                                                         \
        const float4* Wr4 = reinterpret_cast<const float4*>(lw + OFF + (k)*32);\
        const v2*     Wr2 = reinterpret_cast<const v2*>(lw + OFF + (k)*32);   \
        _Pragma("unroll")                                                     \
        for (int j4 = 0; j4 < 7; ++j4) {                                      \
            const float4 w = Wr4[j4];                                         \
            const v2 wlo = { w.x, w.y };                                      \
            const v2 whi = { w.z, w.w };                                      \
            acc[2*j4]   = __builtin_elementwise_fma(sv, wlo, acc[2*j4]);      \
            acc[2*j4+1] = __builtin_elementwise_fma(sv, whi, acc[2*j4+1]);    \
        }                                                                     \
        acc[14] = __builtin_elementwise_fma(sv, Wr2[14], acc[14]);            \
    }
    // SMEM row fma (uniform global W row as v2 -> s_load/SGPR operands).
    #define ROW_FMA_SM(W, k, sv)                                              \
    {                                                                         \
        const v2* Wr = reinterpret_cast<const v2*>(W + (k) * DH);             \
        _Pragma("unroll")                                                     \
        for (int jj = 0; jj < 15; ++jj)                                       \
            acc[jj] = __builtin_elementwise_fma(sv, Wr[jj], acc[jj]);         \
    }
    // LDS row dot (fenced by caller).
    #define ROW_DOT_LDS(OFF, k, G, D)                                         \
    {                                                                         \
        const float4* Wr4 = reinterpret_cast<const float4*>(lw + OFF + (k)*32);\
        const v2*     Wr2 = reinterpret_cast<const v2*>(lw + OFF + (k)*32);   \
        v2 da = (v2){0.f, 0.f}, db = (v2){0.f, 0.f};                          \
        _Pragma("unroll")                                                     \
        for (int j4 = 0; j4 < 7; ++j4) {                                      \
            const float4 w = Wr4[j4];                                         \
            const v2 wlo = { w.x, w.y };                                      \
            const v2 whi = { w.z, w.w };                                      \
            da = __builtin_elementwise_fma(G[2*j4],   wlo, da);               \
            db = __builtin_elementwise_fma(G[2*j4+1], whi, db);               \
        }                                                                     \
        da = __builtin_elementwise_fma(G[14], Wr2[14], da);                   \
        D = (da.x + da.y) + (db.x + db.y);                                    \
    }

    if ((blockIdx.x & 1) == 0) {
        // ================= PATH A: fwd LDS, bwd SMEM (R21) =================
        #pragma unroll
        for (int jj = 0; jj < 15; ++jj) acc[jj] = (v2){0.f, 0.f};
        #pragma unroll
        for (int k = 0; k < 9; ++k) {
            const v2 xv = { x[k], x[k] };
            ROW_FMA(W1_OFF, k, xv);
            SB();
        }
        {
            const v2* bv = reinterpret_cast<const v2*>(lw + B1_OFF);
            #pragma unroll
            for (int jj = 0; jj < 15; ++jj) {
                const v2 z = acc[jj] + bv[jj];
                if (z.x > 0.f) m1 |= (1u << (2*jj));
                if (z.y > 0.f) m1 |= (1u << (2*jj+1));
                hh[jj] = __builtin_elementwise_max(z, z * slope2);
            }
        }
        SB();
        #pragma unroll
        for (int jj = 0; jj < 15; ++jj) acc[jj] = (v2){0.f, 0.f};
        #pragma unroll
        for (int k = 0; k < DH; ++k) {
            const float hk = hh[k >> 1][k & 1];
            const v2 hv = { hk, hk };
            ROW_FMA(W2_OFF, k, hv);
            SB();
        }
        {
            const v2* bv = reinterpret_cast<const v2*>(lw + B2_OFF);
            #pragma unroll
            for (int jj = 0; jj < 15; ++jj) {
                const v2 z = acc[jj] + bv[jj];
                if (z.x > 0.f) m2 |= (1u << (2*jj));
                if (z.y > 0.f) m2 |= (1u << (2*jj+1));
                hh[jj] = __builtin_elementwise_max(z, z * slope2);
            }
        }
        SB();
        #pragma unroll
        for (int jj = 0; jj < 15; ++jj) acc[jj] = (v2){0.f, 0.f};
        #pragma unroll
        for (int k = 0; k < DH; ++k) {
            const float hk = hh[k >> 1][k & 1];
            const v2 hv = { hk, hk };
            ROW_FMA(W3_OFF, k, hv);
            SB();
        }
        {
            const float* b3p = lw + B3_OFF;
            const float* W4p = lw + W4_OFF;
            outv = 0.f;
            #pragma unroll
            for (int j = 0; j < DH; ++j) {
                const float z = acc[j >> 1][j & 1] + b3p[j];
                if (z > 0.f) m3 |= (1u << j);
                const float hz = (z > 0.f) ? z : SLOPE * z;
                outv = fmaf(hz, W4p[j], outv);
            }
            outv += lw[B4_OFF];
        }
        SB();
        // backward via SMEM (paired rows, R21)
        v2 g3[15];
        {
            const v2* w4v = reinterpret_cast<const v2*>(lw + W4_OFF);
            #pragma unroll
            for (int jj = 0; jj < 15; ++jj) {
                const v2 w = w4v[jj];
                g3[jj].x = ((m3 >> (2*jj))   & 1u) ? w.x : SLOPE * w.x;
                g3[jj].y = ((m3 >> (2*jj+1)) & 1u) ? w.y : SLOPE * w.y;
            }
        }
        v2 g2[15];
        #pragma unroll
        for (int k = 0; k < DH; k += 2) {
            v2 dA = (v2){0.f, 0.f}, dB = (v2){0.f, 0.f};
            const v2* WrA = reinterpret_cast<const v2*>(W3 + k * DH);
            const v2* WrB = reinterpret_cast<const v2*>(W3 + (k + 1) * DH);
            #pragma unroll
            for (int jj = 0; jj < 15; ++jj) {
                dA = __builtin_elementwise_fma(g3[jj], WrA[jj], dA);
                dB = __builtin_elementwise_fma(g3[jj], WrB[jj], dB);
            }
            const float dotA = dA.x + dA.y;
            const float dotB = dB.x + dB.y;
            g2[k >> 1].x = ((m2 >> k)       & 1u) ? dotA : SLOPE * dotA;
            g2[k >> 1].y = ((m2 >> (k + 1)) & 1u) ? dotB : SLOPE * dotB;
        }
        v2 g1[15];
        #pragma unroll
        for (int k = 0; k < DH; k += 2) {
            v2 dA = (v2){0.f, 0.f}, dB = (v2){0.f, 0.f};
            const v2* WrA = reinterpret_cast<const v2*>(W2 + k * DH);
            const v2* WrB = reinterpret_cast<const v2*>(W2 + (k + 1) * DH);
            #pragma unroll
            for (int jj = 0; jj < 15; ++jj) {
                dA = __builtin_elementwise_fma(g2[jj], WrA[jj], dA);
                dB = __builtin_elementwise_fma(g2[jj], WrB[jj], dB);
            }
            const float dotA = dA.x + dA.y;
            const float dotB = dB.x + dB.y;
            g1[k >> 1].x = ((m1 >> k)       & 1u) ? dotA : SLOPE * dotA;
            g1[k >> 1].y = ((m1 >> (k + 1)) & 1u) ? dotB : SLOPE * dotB;
        }
        #pragma unroll
        for (int k = 0; k < 9; ++k) {
            v2 d = (v2){0.f, 0.f};
            const v2* Wr = reinterpret_cast<const v2*>(W1 + k * DH);
            #pragma unroll
            for (int jj = 0; jj < 15; ++jj)
                d = __builtin_elementwise_fma(g1[jj], Wr[jj], d);
            gx[k] = d.x + d.y;
        }
    } else {
        // ================= PATH B: fwd SMEM, bwd LDS =================
        #pragma unroll
        for (int jj = 0; jj < 15; ++jj) acc[jj] = (v2){0.f, 0.f};
        #pragma unroll
        for (int k = 0; k < 9; ++k) {
            const v2 xv = { x[k], x[k] };
            ROW_FMA_SM(W1, k, xv);
        }
        {
            const v2* bv = reinterpret_cast<const v2*>(b1);
            #pragma unroll
            for (int jj = 0; jj < 15; ++jj) {
                const v2 z = acc[jj] + bv[jj];
                if (z.x > 0.f) m1 |= (1u << (2*jj));
                if (z.y > 0.f) m1 |= (1u << (2*jj+1));
                hh[jj] = __builtin_elementwise_max(z, z * slope2);
            }
        }
        #pragma unroll
        for (int jj = 0; jj < 15; ++jj) acc[jj] = (v2){0.f, 0.f};
        #pragma unroll
        for (int k = 0; k < DH; ++k) {
            const float hk = hh[k >> 1][k & 1];
            const v2 hv = { hk, hk };
            ROW_FMA_SM(W2, k, hv);
        }
        {
            const v2* bv = reinterpret_cast<const v2*>(b2);
            #pragma unroll
            for (int jj = 0; jj < 15; ++jj) {
                const v2 z = acc[jj] + bv[jj];
                if (z.x > 0.f) m2 |= (1u << (2*jj));
                if (z.y > 0.f) m2 |= (1u << (2*jj+1));
                hh[jj] = __builtin_elementwise_max(z, z * slope2);
            }
        }
        #pragma unroll
        for (int jj = 0; jj < 15; ++jj) acc[jj] = (v2){0.f, 0.f};
        #pragma unroll
        for (int k = 0; k < DH; ++k) {
            const float hk = hh[k >> 1][k & 1];
            const v2 hv = { hk, hk };
            ROW_FMA_SM(W3, k, hv);
        }
        {
            outv = 0.f;
            #pragma unroll
            for (int j = 0; j < DH; ++j) {
                const float z = acc[j >> 1][j & 1] + b3[j];
                if (z > 0.f) m3 |= (1u << j);
                const float hz = (z > 0.f) ? z : SLOPE * z;
                outv = fmaf(hz, W4[j], outv);
            }
            outv += b4[0];
        }
        // backward via LDS (fenced rows, R17)
        v2 g3[15];
        {
            const v2* w4v = reinterpret_cast<const v2*>(lw + W4_OFF);
            #pragma unroll
            for (int jj = 0; jj < 15; ++jj) {
                const v2 w = w4v[jj];
                g3[jj].x = ((m3 >> (2*jj))   & 1u) ? w.x : SLOPE * w.x;
                g3[jj].y = ((m3 >> (2*jj+1)) & 1u) ? w.y : SLOPE * w.y;
            }
        }
        v2 g2[15];
        #pragma unroll
        for (int k = 0; k < DH; ++k) {
            float dot;
            ROW_DOT_LDS(W3_OFF, k, g3, dot);
            g2[k >> 1][k & 1] = ((m2 >> k) & 1u) ? dot : SLOPE * dot;
            SB();
        }
        v2 g1[15];
        #pragma unroll
        for (int k = 0; k < DH; ++k) {
            float dot;
            ROW_DOT_LDS(W2_OFF, k, g2, dot);
            g1[k >> 1][k & 1] = ((m1 >> k) & 1u) ? dot : SLOPE * dot;
            SB();
        }
        #pragma unroll
        for (int k = 0; k < 9; ++k) {
            float dot;
            ROW_DOT_LDS(W1_OFF, k, g1, dot);
            gx[k] = dot;
            SB();
        }
    }

    // ---- stores: [out(N) | h_s(4N) | h_q(N) | h_pe(4N)] ----
    dout[i] = outv;
    float4* hs = reinterpret_cast<float4*>(dout + (size_t)n);
    hs[i] = make_float4(gx[5], gx[6], gx[7], gx[8]);
    dout[(size_t)5 * n + i] = gx[4];
    float4* hpe = reinterpret_cast<float4*>(dout + (size_t)6 * n);
    hpe[i] = make_float4(gx[0], gx[1], gx[2], gx[3]);
}

extern "C" void kernel_launch(void* const* d_in, const int* in_sizes, int n_in,
                              void* d_out, int out_size, void* d_ws, size_t ws_size,
                              hipStream_t stream) {
    const int n = in_sizes[1];  // input_q has N elements
    const int blocks = (n + 255) / 256;
    hipLaunchKernelGGL(mlp_fwdbwd, dim3(blocks), dim3(256), 0, stream,
        (const float4*)d_in[0], (const float*)d_in[1], (const float4*)d_in[2],
        (const float*)d_in[3], (const float*)d_in[4],
        (const float*)d_in[5], (const float*)d_in[6],
        (const float*)d_in[7], (const float*)d_in[8],
        (const float*)d_in[9], (const float*)d_in[10],
        (float*)d_out, n);
}